// Round 6
// baseline (589.379 us; speedup 1.0000x reference)
//
#include <hip/hip_runtime.h>
#include <cstdint>
#include <cstddef>

#define NTOK   16
#define MSTEPS 12
#define HID    128
#define INSZ   32
#define SPB    128    // sequences per block
#define TPB    512    // threads per block (8 waves)

struct KeyArr { uint32_t k0[MSTEPS]; uint32_t k1[MSTEPS]; };

__host__ __device__ static inline uint32_t rotl32(uint32_t x, uint32_t d) {
  return (x << d) | (x >> (32u - d));
}

// Exact replica of JAX's threefry2x32 block cipher.
__host__ __device__ static inline void tf2x32(uint32_t k0, uint32_t k1,
                                              uint32_t x0, uint32_t x1,
                                              uint32_t &o0, uint32_t &o1) {
  const uint32_t ks2 = k0 ^ k1 ^ 0x1BD11BDAu;
  x0 += k0; x1 += k1;
  x0 += x1; x1 = rotl32(x1, 13); x1 ^= x0;
  x0 += x1; x1 = rotl32(x1, 15); x1 ^= x0;
  x0 += x1; x1 = rotl32(x1, 26); x1 ^= x0;
  x0 += x1; x1 = rotl32(x1,  6); x1 ^= x0;
  x0 += k1; x1 += ks2 + 1u;
  x0 += x1; x1 = rotl32(x1, 17); x1 ^= x0;
  x0 += x1; x1 = rotl32(x1, 29); x1 ^= x0;
  x0 += x1; x1 = rotl32(x1, 16); x1 ^= x0;
  x0 += x1; x1 = rotl32(x1, 24); x1 ^= x0;
  x0 += ks2; x1 += k0 + 2u;
  x0 += x1; x1 = rotl32(x1, 13); x1 ^= x0;
  x0 += x1; x1 = rotl32(x1, 15); x1 ^= x0;
  x0 += x1; x1 = rotl32(x1, 26); x1 ^= x0;
  x0 += x1; x1 = rotl32(x1,  6); x1 ^= x0;
  x0 += k0; x1 += k1 + 3u;
  x0 += x1; x1 = rotl32(x1, 17); x1 ^= x0;
  x0 += x1; x1 = rotl32(x1, 29); x1 ^= x0;
  x0 += x1; x1 = rotl32(x1, 16); x1 ^= x0;
  x0 += x1; x1 = rotl32(x1, 24); x1 ^= x0;
  x0 += k1; x1 += ks2 + 4u;
  x0 += x1; x1 = rotl32(x1, 13); x1 ^= x0;
  x0 += x1; x1 = rotl32(x1, 15); x1 ^= x0;
  x0 += x1; x1 = rotl32(x1, 26); x1 ^= x0;
  x0 += x1; x1 = rotl32(x1,  6); x1 ^= x0;
  x0 += ks2; x1 += k0 + 5u;
  o0 = x0; o1 = x1;
}

// Fast HW transcendentals (v_exp_f32 / v_log_f32 are ~1 ulp on gfx950).
__device__ __forceinline__ float fast_exp(float x) {
  return exp2f(x * 1.44269504088896340736f);
}
__device__ __forceinline__ float fast_log(float x) {
  return log2f(x) * 0.69314718055994530942f;
}
__device__ __forceinline__ float fast_tanh(float x) {
  float ax = fabsf(x);
  float e  = exp2f(ax * 2.88539008177792681472f);   // exp(2*ax)
  float r  = 1.0f - 2.0f / (e + 1.0f);
  return copysignf(r, x);
}

// h[k][s] in LDS, 16B-chunk swizzled: logical chunk (s>>2) of row k stored at
// physical chunk (s>>2)^(k&7). GEMM reads (uniform per 32-lane cg-row) are
// bank-conflict-free broadcasts; epilogue column-writes are <=4-way.
__global__ __launch_bounds__(TPB, 4)
void eq_sampler(const float* __restrict__ x0in, const float* __restrict__ h0in,
                const float* __restrict__ Wx,   const float* __restrict__ Wh,
                const float* __restrict__ bvec, const float* __restrict__ Wp,
                const float* __restrict__ bp,   float* __restrict__ out,
                int n, KeyArr keys)
{
  __shared__ float hs[HID * SPB];     // 64 KB
  __shared__ float lgs[SPB * 17];     // staged raw logits
  __shared__ float h1s[HID];          // shared h_1 (identical across seqs)
  __shared__ float z1s[HID];          // shared h_1 @ Wh
  __shared__ float lgs0[NTOK];        // shared logits_0 (raw)
  __shared__ int   ps0_s[SPB], ps1_s[SPB];

  const int tid   = threadIdx.x;
  const int sg    = tid >> 5,  cg = tid & 31;
  const int srow  = sg * 8,    cbase = cg * 4;
  const int c0    = srow >> 2;            // even chunk base
  const int cg16  = cg & 15;
  const int gbase = blockIdx.x * SPB;
  const bool sampler = tid < 2 * SPB;
  const int seq   = tid >> 1,  th = tid & 1;
  const int gseq  = gbase + (sampler ? seq : 0);
  const float TINY = 1.17549435e-38f;

  // ---- prologue A: h_1 = tanh(x0@Wx + h0@Wh + b) — identical for all seqs --
  if (tid < HID) {
    float xw = 0.f;
    for (int k = 0; k < INSZ; ++k) xw = fmaf(x0in[k], Wx[k * HID + tid], xw);
    float a = 0.f;
    for (int k = 0; k < HID; ++k)  a = fmaf(h0in[k], Wh[k * HID + tid], a);
    h1s[tid] = fast_tanh((xw + a) + bvec[tid]);
  }
  __syncthreads();
  // ---- prologue B: z1 = h1@Wh (shared), logits0 = h1@Wp (shared) ----
  if (tid < HID) {
    float a = 0.f;
    for (int k = 0; k < HID; ++k) a = fmaf(h1s[k], Wh[k * HID + tid], a);
    z1s[tid] = a;
  } else if (tid < HID + NTOK) {
    const int j = tid - HID;
    float a = 0.f;
    for (int k = 0; k < HID; ++k) a = fmaf(h1s[k], Wp[k * NTOK + j], a);
    lgs0[j] = a;
  }

  float bb[4], bpv[8];
  #pragma unroll
  for (int c = 0; c < 4; ++c) bb[c] = bvec[cbase + c];
  #pragma unroll
  for (int j = 0; j < 8; ++j) bpv[j] = bp[th * 8 + j];

  // precomputed swizzled LDS word offsets for the GEMM reads (constant)
  int wordA[8];
  #pragma unroll
  for (int kk = 0; kk < 8; ++kk) wordA[kk] = kk * SPB + ((c0 ^ kk) << 2);

  // per-seq state (replicated in both th threads of a pair)
  int cnt = 1, lengths = 1;
  bool act = true, hasvar = false;
  uint64_t pack = 0;

  float* o_seq = out;
  float* o_ent = out + (size_t)n * 12;
  float* o_lp  = out + (size_t)n * 24;
  float* o_cnt = out + (size_t)n * 36;
  float* o_len = out + (size_t)n * 37;
  float* o_msk = out + (size_t)n * 38;

  if (sampler && th == 0 && gseq < n) o_msk[(size_t)gseq * 13] = 1.0f;

  float acc[8][4] = {};
  float accP[8];

  for (int t = 0; t < MSTEPS; ++t) {
    if (t > 0) {
      // ---- fused GEMM: h_cur @ [Wh(4 cols) | Wp(1 col)] — no dup loads ----
      #pragma unroll
      for (int s = 0; s < 8; ++s) {
        accP[s] = 0.f;
        #pragma unroll
        for (int c = 0; c < 4; ++c) acc[s][c] = 0.f;
      }
      const float* wq = Wh + cbase;
      #pragma unroll 1
      for (int oct = 0; oct < 16; ++oct) {
        const int kb = oct * 8;
        const float* wo = wq + (size_t)kb * HID;
        const float* po = Wp + kb * NTOK + cg16;
        #pragma unroll
        for (int kk = 0; kk < 8; ++kk) {
          const float4 ha = *(const float4*)&hs[wordA[kk] + kb * SPB];
          const float4 hb = *(const float4*)&hs[wordA[kk] + kb * SPB + ((kk & 1) ? -4 : 4)];
          const float4 w  = *(const float4*)(wo + kk * HID);
          const float  pw = po[kk * NTOK];
          #pragma unroll
          for (int s = 0; s < 4; ++s) {
            const float hv = s == 0 ? ha.x : s == 1 ? ha.y : s == 2 ? ha.z : ha.w;
            acc[s][0] = fmaf(hv, w.x, acc[s][0]);
            acc[s][1] = fmaf(hv, w.y, acc[s][1]);
            acc[s][2] = fmaf(hv, w.z, acc[s][2]);
            acc[s][3] = fmaf(hv, w.w, acc[s][3]);
            accP[s]   = fmaf(hv, pw,  accP[s]);
          }
          #pragma unroll
          for (int s = 4; s < 8; ++s) {
            const float hv = s == 4 ? hb.x : s == 5 ? hb.y : s == 6 ? hb.z : hb.w;
            acc[s][0] = fmaf(hv, w.x, acc[s][0]);
            acc[s][1] = fmaf(hv, w.y, acc[s][1]);
            acc[s][2] = fmaf(hv, w.z, acc[s][2]);
            acc[s][3] = fmaf(hv, w.w, acc[s][3]);
            accP[s]   = fmaf(hv, pw,  accP[s]);
          }
        }
      }
      if (cg < 16) {
        #pragma unroll
        for (int s = 0; s < 8; ++s) lgs[(srow + s) * 17 + cg] = accP[s];
      }
    }
    __syncthreads();

    // ---- sampling: 2 threads per seq, 8 tokens each (round-5 bit-orders) ----
    if (sampler) {
      float lg[8];
      if (t == 0) {
        #pragma unroll
        for (int j = 0; j < 8; ++j) lg[j] = lgs0[th * 8 + j];
      } else {
        #pragma unroll
        for (int j = 0; j < 8; ++j) lg[j] = lgs[seq * 17 + th * 8 + j];
      }
      #pragma unroll
      for (int j = 0; j < 8; ++j) lg[j] += bpv[j];

      float m8 = lg[0];
      #pragma unroll
      for (int j = 1; j < 8; ++j) m8 = fmaxf(m8, lg[j]);
      float mm = fmaxf(m8, __shfl_xor(m8, 1));

      float e[8]; float Zp = 0.f;
      #pragma unroll
      for (int j = 0; j < 8; ++j) { e[j] = fast_exp(lg[j] - mm); Zp += e[j]; }
      float Z = Zp + __shfl_xor(Zp, 1);

      const int cntv = cnt;
      const int cl   = cntv + t;
      const int hasv = hasvar ? 1 : 0;

      float pr[8]; float Sp = 0.f;
      #pragma unroll
      for (int j = 0; j < 8; ++j) {
        const int tj = th * 8 + j;
        float p = e[j] / Z;
        if (tj >= 8 && cl < 2)                p = 0.f;
        if (tj <  8 && cl > MSTEPS - 2)       p = 0.f;
        if (tj == 8 && cntv == 1 && !hasv)    p = 0.f;
        pr[j] = p; Sp += p;
      }
      float S = Sp + __shfl_xor(Sp, 1);

      float bs = 0.f, blp = 0.f, ep = 0.f; int bj = 0;
      #pragma unroll
      for (int j = 0; j < 8; ++j) {
        const int tj = th * 8 + j;
        float p = pr[j] / S;
        bool pos = p > 0.f;
        float lgpj = pos ? fast_log(p) : -__builtin_inff();
        ep += pos ? p * lgpj : 0.f;
        uint32_t b1, b2;
        tf2x32(keys.k0[t], keys.k1[t], 0u,
               (uint32_t)gseq * 16u + (uint32_t)tj, b1, b2);
        uint32_t bits = b1 ^ b2;
        float uf = __uint_as_float((bits >> 9) | 0x3F800000u) - 1.0f;
        uf += TINY; uf = fmaxf(TINY, uf);
        float g = -fast_log(-fast_log(uf));
        float sc = lgpj + g;
        if (j == 0) { bs = sc; bj = tj; blp = lgpj; }
        else if (sc > bs) { bs = sc; bj = tj; blp = lgpj; }
      }
      {
        float obs  = __shfl_xor(bs, 1);
        int   obj  = __shfl_xor(bj, 1);
        float oblp = __shfl_xor(blp, 1);
        if (obs > bs || (obs == bs && obj < bj)) { bs = obs; bj = obj; blp = oblp; }
      }
      float ent = -(ep + __shfl_xor(ep, 1));
      const int tok = bj;

      // state update (both th threads, identically)
      cnt += -1 + (tok < 4 ? 2 : (tok < 8 ? 1 : 0));
      act = act && (cnt > 0);
      lengths += act ? 1 : 0;
      if (tok >= 9) hasvar = true;
      pack |= (uint64_t)(uint32_t)tok << (4 * t);

      if (th == 0) {
        if (gseq < n) {
          o_ent[(size_t)gseq * 12 + t] = ent;
          o_lp [(size_t)gseq * 12 + t] = blp;
          o_msk[(size_t)gseq * 13 + t + 1] = act ? 1.f : 0.f;
        }
        int np0, np1;
        if (tok < 8) { np0 = tok; np1 = -1; }
        else {
          int c = 0, p0 = -1, p1 = -1;
          for (int i = t; i >= 0; --i) {
            int tk = (int)((pack >> (4 * i)) & 15u);
            c += (tk < 4 ? 2 : (tk < 8 ? 1 : 0)) - 1;
            if (c == 0 && p0 < 0) {
              p0 = tk;
              p1 = (i < t) ? (int)((pack >> (4 * (i + 1))) & 15u) : -1;
            }
          }
          np0 = p0; np1 = p1;
        }
        ps0_s[seq] = np0; ps1_s[seq] = np1;
      }
    }
    __syncthreads();

    if (t < MSTEPS - 1) {
      // ---- epilogue: h_next = tanh((xw + z) + b), write swizzled to hs ----
      float val[8][4];
      #pragma unroll
      for (int s = 0; s < 8; ++s) {
        const int sq = srow + s;
        const int p0 = ps0_s[sq], p1 = ps1_s[sq];
        float4 a  = make_float4(0.f, 0.f, 0.f, 0.f);
        float4 cv = make_float4(0.f, 0.f, 0.f, 0.f);
        if (p0 >= 0) a  = *(const float4*)&Wx[p0 * HID + cbase];
        if (p1 >= 0) cv = *(const float4*)&Wx[(NTOK + p1) * HID + cbase];
        float xw[4] = {a.x + cv.x, a.y + cv.y, a.z + cv.z, a.w + cv.w};
        #pragma unroll
        for (int c = 0; c < 4; ++c) {
          float zz = (t == 0) ? z1s[cbase + c] : acc[s][c];
          val[s][c] = fast_tanh((xw[c] + zz) + bb[c]);
        }
      }
      #pragma unroll
      for (int c = 0; c < 4; ++c) {
        const int col = cbase + c;
        const int wb  = col * SPB + ((c0 ^ (col & 7)) << 2);
        *(float4*)&hs[wb] =
            make_float4(val[0][c], val[1][c], val[2][c], val[3][c]);
        *(float4*)&hs[wb ^ 4] =
            make_float4(val[4][c], val[5][c], val[6][c], val[7][c]);
      }
    }
    __syncthreads();
  }

  if (sampler && th == 0 && gseq < n) {
    o_cnt[gseq] = (float)cnt;
    o_len[gseq] = (float)lengths;
    #pragma unroll
    for (int j = 0; j < MSTEPS; ++j)
      o_seq[(size_t)gseq * 12 + j] = (float)((pack >> (4 * j)) & 15u);
  }
}

extern "C" void kernel_launch(void* const* d_in, const int* in_sizes, int n_in,
                              void* d_out, int out_size, void* d_ws, size_t ws_size,
                              hipStream_t stream) {
  const float* x0 = (const float*)d_in[1];
  const float* h0 = (const float*)d_in[2];
  const float* Wx = (const float*)d_in[3];
  const float* Wh = (const float*)d_in[4];
  const float* bv = (const float*)d_in[5];
  const float* Wp = (const float*)d_in[6];
  const float* bp = (const float*)d_in[7];
  float* out = (float*)d_out;

  int n = out_size / 51;   // 12+12+12+1+1+13 floats per sequence

  // jax.random.split(jax.random.key(42), 12), partitionable threefry:
  // keys[t] = threefry((0,42), (0, t)).
  KeyArr ka;
  for (int t = 0; t < 12; ++t) {
    uint32_t o0, o1;
    tf2x32(0u, 42u, 0u, (uint32_t)t, o0, o1);
    ka.k0[t] = o0; ka.k1[t] = o1;
  }

  int blocks = (n + SPB - 1) / SPB;
  eq_sampler<<<blocks, TPB, 0, stream>>>(x0, h0, Wx, Wh, bv, Wp, bp, out, n, ka);
}

// Round 7
// 508.017 us; speedup vs baseline: 1.1602x; 1.1602x over previous
//
#include <hip/hip_runtime.h>
#include <cstdint>
#include <cstddef>

#define NTOK   16
#define MSTEPS 12
#define HID    128
#define INSZ   32
#define SPB    64     // sequences per block
#define TPB    256    // threads per block (4 waves)

struct KeyArr { uint32_t k0[MSTEPS]; uint32_t k1[MSTEPS]; };

__host__ __device__ static inline uint32_t rotl32(uint32_t x, uint32_t d) {
  return (x << d) | (x >> (32u - d));
}

// Exact replica of JAX's threefry2x32 block cipher.
__host__ __device__ static inline void tf2x32(uint32_t k0, uint32_t k1,
                                              uint32_t x0, uint32_t x1,
                                              uint32_t &o0, uint32_t &o1) {
  const uint32_t ks2 = k0 ^ k1 ^ 0x1BD11BDAu;
  x0 += k0; x1 += k1;
  x0 += x1; x1 = rotl32(x1, 13); x1 ^= x0;
  x0 += x1; x1 = rotl32(x1, 15); x1 ^= x0;
  x0 += x1; x1 = rotl32(x1, 26); x1 ^= x0;
  x0 += x1; x1 = rotl32(x1,  6); x1 ^= x0;
  x0 += k1; x1 += ks2 + 1u;
  x0 += x1; x1 = rotl32(x1, 17); x1 ^= x0;
  x0 += x1; x1 = rotl32(x1, 29); x1 ^= x0;
  x0 += x1; x1 = rotl32(x1, 16); x1 ^= x0;
  x0 += x1; x1 = rotl32(x1, 24); x1 ^= x0;
  x0 += ks2; x1 += k0 + 2u;
  x0 += x1; x1 = rotl32(x1, 13); x1 ^= x0;
  x0 += x1; x1 = rotl32(x1, 15); x1 ^= x0;
  x0 += x1; x1 = rotl32(x1, 26); x1 ^= x0;
  x0 += x1; x1 = rotl32(x1,  6); x1 ^= x0;
  x0 += k0; x1 += k1 + 3u;
  x0 += x1; x1 = rotl32(x1, 17); x1 ^= x0;
  x0 += x1; x1 = rotl32(x1, 29); x1 ^= x0;
  x0 += x1; x1 = rotl32(x1, 16); x1 ^= x0;
  x0 += x1; x1 = rotl32(x1, 24); x1 ^= x0;
  x0 += k1; x1 += ks2 + 4u;
  x0 += x1; x1 = rotl32(x1, 13); x1 ^= x0;
  x0 += x1; x1 = rotl32(x1, 15); x1 ^= x0;
  x0 += x1; x1 = rotl32(x1, 26); x1 ^= x0;
  x0 += x1; x1 = rotl32(x1,  6); x1 ^= x0;
  x0 += ks2; x1 += k0 + 5u;
  o0 = x0; o1 = x1;
}

// Fast transcendentals on the HW pipes (v_exp_f32 / v_log_f32 / v_rcp_f32,
// each ~1 ulp on gfx950). __expf/__logf are the HIP native-intrinsic forms.
__device__ __forceinline__ float fast_exp(float x) { return __expf(x); }
__device__ __forceinline__ float fast_log(float x) { return __logf(x); }
__device__ __forceinline__ float fast_tanh(float x) {
  float ax = fabsf(x);
  float e  = __expf(2.0f * ax);
  float r  = fmaf(-2.0f, __builtin_amdgcn_rcpf(e + 1.0f), 1.0f);
  return copysignf(r, x);
}

// h[k][s] in LDS, 16B-chunk swizzled: logical chunk (s>>2) stored at physical
// chunk (s>>2)^((k>>3)&15). Reads (fixed k, 4 consecutive s) and writes
// (fixed col k, 4 consecutive s) are both b128 and >=2-way-conflict-free.
__global__ __launch_bounds__(TPB)
void eq_sampler(const float* __restrict__ x0in, const float* __restrict__ h0in,
                const float* __restrict__ Wx,   const float* __restrict__ Wh,
                const float* __restrict__ bvec, const float* __restrict__ Wp,
                const float* __restrict__ bp,   float* __restrict__ out,
                int n, KeyArr keys)
{
  __shared__ float hs[HID * SPB];     // 32 KB
  __shared__ float lgs[SPB * 17];     // staged raw logits (stride 17)
  __shared__ float h1s[HID];          // shared h_1 (identical across seqs)
  __shared__ float z1s[HID];          // shared h_1 @ Wh
  __shared__ float lgs0[NTOK];        // shared logits_0 (raw)
  __shared__ int   ps0_s[SPB], ps1_s[SPB];

  const int tid   = threadIdx.x;
  const int sg    = tid >> 4,  cg = tid & 15;
  const int srow  = sg * 4,    cbase = cg * 8;
  const int gbase = blockIdx.x * SPB;
  const bool sampler = tid < 2 * SPB;
  const int seq   = tid >> 1,  th = tid & 1;      // valid when sampler
  const int gseq  = gbase + (sampler ? seq : 0);
  const float TINY = 1.17549435e-38f;

  // ---- prologue A: h_1 = tanh(x0@Wx + h0@Wh + b) — identical for all seqs --
  if (tid < HID) {
    float xw = 0.f;
    for (int k = 0; k < INSZ; ++k) xw = fmaf(x0in[k], Wx[k * HID + tid], xw);
    float a = 0.f;
    for (int k = 0; k < HID; ++k)  a = fmaf(h0in[k], Wh[k * HID + tid], a);
    h1s[tid] = fast_tanh((xw + a) + bvec[tid]);
  }
  __syncthreads();
  // ---- prologue B: z1 = h1@Wh (shared), logits0 = h1@Wp (shared) ----
  if (tid < HID) {
    float a = 0.f;
    for (int k = 0; k < HID; ++k) a = fmaf(h1s[k], Wh[k * HID + tid], a);
    z1s[tid] = a;
  } else if (tid < HID + NTOK) {
    const int j = tid - HID;
    float a = 0.f;
    for (int k = 0; k < HID; ++k) a = fmaf(h1s[k], Wp[k * NTOK + j], a);
    lgs0[j] = a;
  }

  float bb[8], bpv[8];
  #pragma unroll
  for (int c = 0; c < 8; ++c) bb[c] = bvec[cbase + c];
  #pragma unroll
  for (int j = 0; j < 8; ++j) bpv[j] = bp[th * 8 + j];

  // per-seq state (replicated in both th threads of a pair)
  int cnt = 1, lengths = 1;
  bool act = true, hasvar = false;
  uint64_t pack = 0;

  float* o_seq = out;
  float* o_ent = out + (size_t)n * 12;
  float* o_lp  = out + (size_t)n * 24;
  float* o_cnt = out + (size_t)n * 36;
  float* o_len = out + (size_t)n * 37;
  float* o_msk = out + (size_t)n * 38;

  if (sampler && th == 0 && gseq < n) o_msk[(size_t)gseq * 13] = 1.0f;

  float acc[4][8];
  float accP[4];

  for (int t = 0; t < MSTEPS; ++t) {
    if (t > 0) {
      // ---- fused GEMM: h_cur @ [Wh | Wp-col(cg)] ----
      #pragma unroll
      for (int s = 0; s < 4; ++s) {
        accP[s] = 0.f;
        #pragma unroll
        for (int c = 0; c < 8; ++c) acc[s][c] = 0.f;
      }
      #pragma unroll 1
      for (int oct = 0; oct < 16; ++oct) {
        const int kb   = oct * 8;
        const int hw   = kb * SPB + ((sg ^ oct) << 2);   // word offset
        const float* wo = Wh + (size_t)kb * HID + cbase;
        const float* po = Wp + kb * NTOK + cg;
        #pragma unroll
        for (int kk = 0; kk < 8; ++kk) {
          float4 h4 = *(const float4*)&hs[hw + kk * SPB];
          float4 w0 = *(const float4*)(wo + kk * HID);
          float4 w1 = *(const float4*)(wo + kk * HID + 4);
          float  pw = po[kk * NTOK];
          #pragma unroll
          for (int s = 0; s < 4; ++s) {
            const float hv = s == 0 ? h4.x : s == 1 ? h4.y : s == 2 ? h4.z : h4.w;
            acc[s][0] = fmaf(hv, w0.x, acc[s][0]);
            acc[s][1] = fmaf(hv, w0.y, acc[s][1]);
            acc[s][2] = fmaf(hv, w0.z, acc[s][2]);
            acc[s][3] = fmaf(hv, w0.w, acc[s][3]);
            acc[s][4] = fmaf(hv, w1.x, acc[s][4]);
            acc[s][5] = fmaf(hv, w1.y, acc[s][5]);
            acc[s][6] = fmaf(hv, w1.z, acc[s][6]);
            acc[s][7] = fmaf(hv, w1.w, acc[s][7]);
            accP[s]   = fmaf(hv, pw,   accP[s]);
          }
        }
      }
      // stage raw logits
      #pragma unroll
      for (int s = 0; s < 4; ++s) lgs[(srow + s) * 17 + cg] = accP[s];
    }
    __syncthreads();

    // ---- sampling: 2 threads per seq, 8 tokens each (round-3 bit-orders) ----
    if (sampler) {
      float lg[8];
      if (t == 0) {
        #pragma unroll
        for (int j = 0; j < 8; ++j) lg[j] = lgs0[th * 8 + j];
      } else {
        #pragma unroll
        for (int j = 0; j < 8; ++j) lg[j] = lgs[seq * 17 + th * 8 + j];
      }
      #pragma unroll
      for (int j = 0; j < 8; ++j) lg[j] += bpv[j];

      float m8 = lg[0];
      #pragma unroll
      for (int j = 1; j < 8; ++j) m8 = fmaxf(m8, lg[j]);
      float mm = fmaxf(m8, __shfl_xor(m8, 1));

      float e[8]; float Zp = 0.f;
      #pragma unroll
      for (int j = 0; j < 8; ++j) { e[j] = fast_exp(lg[j] - mm); Zp += e[j]; }
      float Z = Zp + __shfl_xor(Zp, 1);

      const int cntv = cnt;
      const int cl   = cntv + t;
      const int hasv = hasvar ? 1 : 0;

      float pr[8]; float Sp = 0.f;
      #pragma unroll
      for (int j = 0; j < 8; ++j) {
        const int tj = th * 8 + j;
        float p = e[j] / Z;
        if (tj >= 8 && cl < 2)                p = 0.f;
        if (tj <  8 && cl > MSTEPS - 2)       p = 0.f;
        if (tj == 8 && cntv == 1 && !hasv)    p = 0.f;
        pr[j] = p; Sp += p;
      }
      float S = Sp + __shfl_xor(Sp, 1);

      float bs = 0.f, blp = 0.f, ep = 0.f; int bj = 0;
      #pragma unroll
      for (int j = 0; j < 8; ++j) {
        const int tj = th * 8 + j;
        float p = pr[j] / S;
        bool pos = p > 0.f;
        float lgpj = pos ? fast_log(p) : -__builtin_inff();
        ep += pos ? p * lgpj : 0.f;
        uint32_t b1, b2;
        tf2x32(keys.k0[t], keys.k1[t], 0u,
               (uint32_t)gseq * 16u + (uint32_t)tj, b1, b2);
        uint32_t bits = b1 ^ b2;
        float uf = __uint_as_float((bits >> 9) | 0x3F800000u) - 1.0f;
        uf += TINY; uf = fmaxf(TINY, uf);
        float g = -fast_log(-fast_log(uf));
        float sc = lgpj + g;
        if (j == 0) { bs = sc; bj = tj; blp = lgpj; }
        else if (sc > bs) { bs = sc; bj = tj; blp = lgpj; }
      }
      {
        float obs  = __shfl_xor(bs, 1);
        int   obj  = __shfl_xor(bj, 1);
        float oblp = __shfl_xor(blp, 1);
        if (obs > bs || (obs == bs && obj < bj)) { bs = obs; bj = obj; blp = oblp; }
      }
      float ent = -(ep + __shfl_xor(ep, 1));
      const int tok = bj;

      // state update (both th threads, identically)
      cnt += -1 + (tok < 4 ? 2 : (tok < 8 ? 1 : 0));
      act = act && (cnt > 0);
      lengths += act ? 1 : 0;
      if (tok >= 9) hasvar = true;
      pack |= (uint64_t)(uint32_t)tok << (4 * t);

      if (th == 0) {
        if (gseq < n) {
          o_ent[(size_t)gseq * 12 + t] = ent;
          o_lp [(size_t)gseq * 12 + t] = blp;
          o_msk[(size_t)gseq * 13 + t + 1] = act ? 1.f : 0.f;
        }
        // parent & sibling from packed tokens
        int np0, np1;
        if (tok < 8) { np0 = tok; np1 = -1; }
        else {
          int c = 0, p0 = -1, p1 = -1;
          for (int i = t; i >= 0; --i) {
            int tk = (int)((pack >> (4 * i)) & 15u);
            c += (tk < 4 ? 2 : (tk < 8 ? 1 : 0)) - 1;
            if (c == 0 && p0 < 0) {
              p0 = tk;
              p1 = (i < t) ? (int)((pack >> (4 * (i + 1))) & 15u) : -1;
            }
          }
          np0 = p0; np1 = p1;
        }
        ps0_s[seq] = np0; ps1_s[seq] = np1;
      }
    }
    __syncthreads();

    if (t < MSTEPS - 1) {
      // ---- epilogue: h_next = tanh((xw + z) + b), write to hs ----
      #pragma unroll
      for (int s = 0; s < 4; ++s) {
        const int sq = srow + s;
        const int p0 = ps0_s[sq], p1 = ps1_s[sq];
        float av[8], cv[8];
        #pragma unroll
        for (int c = 0; c < 8; ++c) { av[c] = 0.f; cv[c] = 0.f; }
        if (p0 >= 0) {
          float4 u0 = *(const float4*)&Wx[p0 * HID + cbase];
          float4 u1 = *(const float4*)&Wx[p0 * HID + cbase + 4];
          av[0]=u0.x; av[1]=u0.y; av[2]=u0.z; av[3]=u0.w;
          av[4]=u1.x; av[5]=u1.y; av[6]=u1.z; av[7]=u1.w;
        }
        if (p1 >= 0) {
          float4 u0 = *(const float4*)&Wx[(NTOK + p1) * HID + cbase];
          float4 u1 = *(const float4*)&Wx[(NTOK + p1) * HID + cbase + 4];
          cv[0]=u0.x; cv[1]=u0.y; cv[2]=u0.z; cv[3]=u0.w;
          cv[4]=u1.x; cv[5]=u1.y; cv[6]=u1.z; cv[7]=u1.w;
        }
        #pragma unroll
        for (int c = 0; c < 8; ++c) {
          float zz = t == 0 ? z1s[cbase + c] : acc[s][c];
          acc[s][c] = fast_tanh(((av[c] + cv[c]) + zz) + bb[c]);
        }
      }
      const int wbase = ((sg ^ cg) << 2);
      #pragma unroll
      for (int c = 0; c < 8; ++c) {
        *(float4*)&hs[(cbase + c) * SPB + wbase] =
            make_float4(acc[0][c], acc[1][c], acc[2][c], acc[3][c]);
      }
    }
    __syncthreads();
  }

  if (sampler && th == 0 && gseq < n) {
    o_cnt[gseq] = (float)cnt;
    o_len[gseq] = (float)lengths;
    #pragma unroll
    for (int j = 0; j < MSTEPS; ++j)
      o_seq[(size_t)gseq * 12 + j] = (float)((pack >> (4 * j)) & 15u);
  }
}

extern "C" void kernel_launch(void* const* d_in, const int* in_sizes, int n_in,
                              void* d_out, int out_size, void* d_ws, size_t ws_size,
                              hipStream_t stream) {
  const float* x0 = (const float*)d_in[1];
  const float* h0 = (const float*)d_in[2];
  const float* Wx = (const float*)d_in[3];
  const float* Wh = (const float*)d_in[4];
  const float* bv = (const float*)d_in[5];
  const float* Wp = (const float*)d_in[6];
  const float* bp = (const float*)d_in[7];
  float* out = (float*)d_out;

  int n = out_size / 51;   // 12+12+12+1+1+13 floats per sequence

  // jax.random.split(jax.random.key(42), 12), partitionable threefry:
  // keys[t] = threefry((0,42), (0, t)).
  KeyArr ka;
  for (int t = 0; t < 12; ++t) {
    uint32_t o0, o1;
    tf2x32(0u, 42u, 0u, (uint32_t)t, o0, o1);
    ka.k0[t] = o0; ka.k1[t] = o1;
  }

  int blocks = (n + SPB - 1) / SPB;
  eq_sampler<<<blocks, TPB, 0, stream>>>(x0, h0, Wx, Wh, bv, Wp, bp, out, n, ka);
}